// Round 1
// baseline (86.563 us; speedup 1.0000x reference)
//
#include <hip/hip_runtime.h>
#include <math.h>

// KDE via GEMM trick, v14 = v13 restructured for 8 waves/SIMD occupancy.
//   density[i] = (1/M) * sum_j exp2(-C2*sq_ij - log2(M))
//   sq_ij = |x_i|^2 + |d_j|^2 - 2*dot(x_i,d_j)
//
// CROSS-ROUND MODEL (r9-v13, H~56.5us fixed harness: 42us ws-poison fill
// + restore/prep/gaps): main plateaued ~29-30us across r9-v13. Pipe
// accounting per SIMD at 4 waves: VALU ~3.7us, MFMA ~2.1us, LDS ~2.6us --
// even zero-overlap sums to ~8.4us, so main is ~70% STALLED, not
// throughput-bound on any pipe. Bytes (r11), latency-depth (r12), and
// VMEM dedup (v13, -1us) all falsified as primary bottleneck.
//
// v14: double wave-level concurrency. Halve rows/wave (32 -> 16: one A
// row-tile, af[4]=16 VGPR instead of 32), shrinking named state to ~60
// VGPR so the allocator can hit <=64 -> 8 waves/SIMD (pinned (8,8)).
// Grid 2048 = 8 blocks/CU, LDS 16KB x 8 = 128KB <= 160KB. Per-pipe totals
// unchanged (2x waves x half work); independent streams per SIMD double.
// Also prefetch the per-pair dv loads one iteration ahead (compiler can't
// hoist them across __syncthreads; they were consumed ~10 instrs after
// issue = a dependent global load on the critical path every pair).
// Barrier discipline unchanged from v13 (2 tiles/barrier, stage issued
// after the barrier so each barrier drains loads issued a full compute
// phase earlier).
//
// Fragment mappings (verified end-to-end rounds 2-13):
//   A: lane holds A[m=lane&15][k=(lane>>4)*8+j]
//   B: lane holds B^T row-major: col=lane&15, k=(lane>>4)*8+j
//   C/D: col=lane&15, row=(lane>>4)*4+reg
// global_load_lds: LDS dest = wave-uniform base + lane*16 (verified m104);
// df's fragment-major layout matches exactly.
// fp16 single-pass accuracy verified r4-v13: absmax 2.8e-17 vs 2.4e-16.

#define D_DIM 128
#define TPG   32   // 16-col tiles per col-group (512 cols); 16 pairs

typedef _Float16 f16x8 __attribute__((ext_vector_type(8)));
typedef _Float16 f16x4 __attribute__((ext_vector_type(4)));
typedef __attribute__((ext_vector_type(4))) float f32x4;

#define C2F ((float)(0.5 / 2.50662827463100050242 * 1.44269504088896340736))

// ---- prep: fp32 -> fp16 fragment-major + pre-scaled norms ----------------
__global__ __launch_bounds__(256)
void prep_kernel(const float* __restrict__ x, const float* __restrict__ data,
                 _Float16* __restrict__ xf, _Float16* __restrict__ df,
                 float* __restrict__ xn_u, float* __restrict__ dn_s,
                 int xThreads, float negLogM) {
    const int gid = blockIdx.x * 256 + threadIdx.x;
    const int which = (gid >= xThreads);
    const int id = which ? (gid - xThreads) : gid;
    const int row = id >> 5, seg = id & 31;
    const float* src = which ? data : x;
    _Float16* dst = which ? df : xf;

    const float4 v = *(const float4*)&src[(size_t)row * D_DIM + seg * 4];

    const int t = row >> 4, r = row & 15;
    const int kc = seg >> 3, q = (seg >> 1) & 3, j0 = (seg & 1) * 4;
    f16x4 h;
    h[0] = (_Float16)v.x; h[1] = (_Float16)v.y;
    h[2] = (_Float16)v.z; h[3] = (_Float16)v.w;
    *(f16x4*)&dst[((size_t)(t * 4 + kc) * 64 + q * 16 + r) * 8 + j0] = h;

    float nrm = fmaf(v.x, v.x, fmaf(v.y, v.y, fmaf(v.z, v.z, v.w * v.w)));
#pragma unroll
    for (int off = 1; off < 32; off <<= 1) nrm += __shfl_xor(nrm, off, 64);
    if (seg == 0) {
        if (which) dn_s[row] = -C2F * nrm;
        else       xn_u[row] = fmaf(-C2F, nrm, negLogM);
    }
}

// ---- main: 4 waves x 16 rows, LDS-shared B, 2 tiles per barrier ----------
// 8 blocks/CU at pinned waves_per_eu(8,8) -> 8 waves/SIMD.
__global__ __launch_bounds__(256)
__attribute__((amdgpu_waves_per_eu(8, 8)))
void kde_f16v14(const _Float16* __restrict__ xf, const _Float16* __restrict__ df,
                const float* __restrict__ xn_u, const float* __restrict__ dn_s,
                float* __restrict__ out, int colGroups) {
    // Double buffer: each holds a PAIR of 16-col B tiles (2 x 4 KB).
    // Chunk c = m*4+kc (m=member 0/1) lives at sh[buf][c*512 .. +512);
    // fragment (kc,lane) of member m at sh[buf][(m*4+kc)*512 + lane*8].
    __shared__ _Float16 sh[2][4096];

    const int tid  = threadIdx.x;
    const int lane = tid & 63;
    const int w    = tid >> 6;
    const int q    = lane >> 4;
    const int r    = lane & 15;

    const int bid = blockIdx.x;
    const int cg  = bid % colGroups;
    const int rb  = bid / colGroups;
    const int rowBase  = rb * 64 + w * 16;   // this wave's 16 rows
    const int colTile0 = cg * TPG;

    const float twoC2 = 2.0f * C2F;

    // A fragments: 4 coalesced dwordx4 loads, once (1 row-tile).
    f16x8 af[4];
    {
        const int tG = rb * 4 + w;
#pragma unroll
        for (int kc = 0; kc < 4; ++kc)
            af[kc] = *(const f16x8*)&xf[((size_t)(tG * 4 + kc) * 64 + lane) * 8];
    }

    const f32x4 u0 = *(const f32x4*)&xn_u[rowBase + q * 4];

    f32x4 srow = (f32x4){0.f, 0.f, 0.f, 0.f};

    const _Float16* dbase = &df[(size_t)colTile0 * 2048];   // 2048 halves/tile
    const float*    nbase = &dn_s[colTile0 * 16 + r];

    // Stage pair p into buffer buf: 8 chunks of 1 KB, 2 per wave.
    // Wave-uniform LDS base + lane*16 (HW scatter) matches df layout.
    auto stagePair = [&](int p, int buf) {
#pragma unroll
        for (int i = 0; i < 2; ++i) {
            const int c  = w * 2 + i;          // 0..7
            const int m  = c >> 2, kc = c & 3;
            const _Float16* g = &dbase[(size_t)(p * 2 + m) * 2048 + (size_t)kc * 512 + (size_t)lane * 8];
            __builtin_amdgcn_global_load_lds(
                (const __attribute__((address_space(1))) void*)g,
                (__attribute__((address_space(3))) void*)&sh[buf][c * 512], 16, 0, 0);
        }
    };

// Compute one 16-col tile (member M of the current pair) from LDS.
#define TILE(BUF, M, DVV)                                                         \
    {                                                                             \
        f16x8 b0 = *(const f16x8*)&sh[BUF][((M) * 4 + 0) * 512 + lane * 8];       \
        f16x8 b1 = *(const f16x8*)&sh[BUF][((M) * 4 + 1) * 512 + lane * 8];       \
        f16x8 b2 = *(const f16x8*)&sh[BUF][((M) * 4 + 2) * 512 + lane * 8];       \
        f16x8 b3 = *(const f16x8*)&sh[BUF][((M) * 4 + 3) * 512 + lane * 8];       \
        f32x4 a0 = (f32x4){0.f, 0.f, 0.f, 0.f};                                   \
        a0 = __builtin_amdgcn_mfma_f32_16x16x32_f16(af[0], b0, a0, 0, 0, 0);      \
        a0 = __builtin_amdgcn_mfma_f32_16x16x32_f16(af[1], b1, a0, 0, 0, 0);      \
        a0 = __builtin_amdgcn_mfma_f32_16x16x32_f16(af[2], b2, a0, 0, 0, 0);      \
        a0 = __builtin_amdgcn_mfma_f32_16x16x32_f16(af[3], b3, a0, 0, 0, 0);      \
        const float edv_ = __builtin_amdgcn_exp2f(DVV);                           \
        srow[0] = fmaf(__builtin_amdgcn_exp2f(fmaf(twoC2, a0[0], u0[0])), edv_, srow[0]); \
        srow[1] = fmaf(__builtin_amdgcn_exp2f(fmaf(twoC2, a0[1], u0[1])), edv_, srow[1]); \
        srow[2] = fmaf(__builtin_amdgcn_exp2f(fmaf(twoC2, a0[2], u0[2])), edv_, srow[2]); \
        srow[3] = fmaf(__builtin_amdgcn_exp2f(fmaf(twoC2, a0[3], u0[3])), edv_, srow[3]); \
    }

    stagePair(0, 0);
    // dv prologue loads (consumed in iteration 0; thereafter one pair ahead).
    float dv0 = nbase[0];
    float dv1 = nbase[16];

#pragma unroll 1
    for (int p = 0; p < TPG / 2; ++p) {
        const int buf = p & 1;
        __syncthreads();                    // drains stage(p) (issued a full
                                            // compute phase ago) + frees buf^1
        float ndv0 = dv0, ndv1 = dv1;
        if (p + 1 < TPG / 2) {
            stagePair(p + 1, buf ^ 1);      // in flight across this compute
            ndv0 = nbase[(p * 2 + 2) * 16]; // dv prefetch: one pair ahead
            ndv1 = nbase[(p * 2 + 3) * 16];
        }
        TILE(buf, 0, dv0);
        TILE(buf, 1, dv1);
        dv0 = ndv0; dv1 = ndv1;
    }

#undef TILE

    // Reduce over the 16 col-lanes (r) and accumulate to out.
#pragma unroll
    for (int p = 0; p < 4; ++p) {
        float s = srow[p];
        s += __shfl_xor(s, 1, 64);
        s += __shfl_xor(s, 2, 64);
        s += __shfl_xor(s, 4, 64);
        s += __shfl_xor(s, 8, 64);
        if (r == 0) atomicAdd(&out[rowBase + q * 4 + p], s);
    }
}

// ---------------- fallback: round-1 VALU kernel (any size, no ws) ---------
#define BN 128
#define BM 128
#define KT 32
#define LDSS 132

__global__ __launch_bounds__(256, 4)
void kde_valu(const float* __restrict__ x, const float* __restrict__ data,
              float* __restrict__ out, int N, int M) {
    __shared__ float xs[KT][LDSS];
    __shared__ float dsh[KT][LDSS];
    __shared__ float xn_s[BN];
    __shared__ float dn_s[BM];
    const int tid = threadIdx.x;
    const int ty = tid >> 4, tx = tid & 15;
    const int rowBase = blockIdx.y * BN, colBase = blockIdx.x * BM;
    float acc[8][8];
#pragma unroll
    for (int i = 0; i < 8; ++i)
#pragma unroll
        for (int j = 0; j < 8; ++j) acc[i][j] = 0.0f;
    float normAcc = 0.0f;
    for (int kc = 0; kc < D_DIM; kc += KT) {
        __syncthreads();
#pragma unroll
        for (int i = 0; i < 4; ++i) {
            const int idx = tid + i * 256;
            const int row = idx >> 3, kq = idx & 7;
            const float4 v = *(const float4*)&x[(size_t)(rowBase + row) * D_DIM + kc + kq * 4];
            xs[kq * 4 + 0][row] = v.x; xs[kq * 4 + 1][row] = v.y;
            xs[kq * 4 + 2][row] = v.z; xs[kq * 4 + 3][row] = v.w;
            const float4 wv = *(const float4*)&data[(size_t)(colBase + row) * D_DIM + kc + kq * 4];
            dsh[kq * 4 + 0][row] = wv.x; dsh[kq * 4 + 1][row] = wv.y;
            dsh[kq * 4 + 2][row] = wv.z; dsh[kq * 4 + 3][row] = wv.w;
        }
        __syncthreads();
        {
            const float* col = (tid < 128) ? &xs[0][tid] : &dsh[0][tid - 128];
#pragma unroll
            for (int k = 0; k < KT; ++k) { const float v = col[k * LDSS]; normAcc = fmaf(v, v, normAcc); }
        }
#pragma unroll
        for (int k = 0; k < KT; ++k) {
            float a[8], b[8];
            *(float4*)&a[0] = *(const float4*)&xs[k][ty * 8];
            *(float4*)&a[4] = *(const float4*)&xs[k][ty * 8 + 4];
            *(float4*)&b[0] = *(const float4*)&dsh[k][tx * 4];
            *(float4*)&b[4] = *(const float4*)&dsh[k][64 + tx * 4];
#pragma unroll
            for (int i = 0; i < 8; ++i)
#pragma unroll
                for (int j = 0; j < 8; ++j) acc[i][j] = fmaf(a[i], b[j], acc[i][j]);
        }
    }
    if (tid < 128) xn_s[tid] = normAcc; else dn_s[tid - 128] = normAcc;
    __syncthreads();
    const float C2 = C2F;
    const float negLogM = -log2f((float)M);
#pragma unroll
    for (int i = 0; i < 8; ++i) {
        const int row = ty * 8 + i;
        const float xnr = xn_s[row];
        float s = 0.0f;
#pragma unroll
        for (int j = 0; j < 8; ++j) {
            const int col = (j < 4) ? (tx * 4 + j) : (64 + tx * 4 + (j - 4));
            const float sq = xnr + dn_s[col] - 2.0f * acc[i][j];
            s += exp2f(fmaf(-C2, sq, negLogM));
        }
#pragma unroll
        for (int off = 1; off < 16; off <<= 1) s += __shfl_xor(s, off, 64);
        if (tx == 0) atomicAdd(&out[rowBase + row], s);
    }
}

extern "C" void kernel_launch(void* const* d_in, const int* in_sizes, int n_in,
                              void* d_out, int out_size, void* d_ws, size_t ws_size,
                              hipStream_t stream) {
    const float* x    = (const float*)d_in[0];
    const float* data = (const float*)d_in[1];
    float* out = (float*)d_out;
    const int N = in_sizes[0] / D_DIM;
    const int M = in_sizes[1] / D_DIM;

    hipMemsetAsync(d_out, 0, (size_t)out_size * sizeof(float), stream);

    const size_t need = (size_t)(N + M) * D_DIM * 2 + (size_t)(N + M) * 4;
    if (ws_size < need || (N & 63) || (M & 511)) {
        dim3 grid(M / BM, N / BN);
        kde_valu<<<grid, 256, 0, stream>>>(x, data, out, N, M);
        return;
    }

    _Float16* xf = (_Float16*)d_ws;
    _Float16* df = xf + (size_t)N * D_DIM;
    float* xn_u = (float*)(df + (size_t)M * D_DIM);
    float* dn_s = xn_u + N;

    const float negLogM = -log2f((float)M);
    const int xThreads = N * 32;
    const int totThreads = (N + M) * 32;
    prep_kernel<<<totThreads / 256, 256, 0, stream>>>(x, data, xf, df, xn_u, dn_s,
                                                      xThreads, negLogM);

    const int colGroups = M / 512;           // 512 cols/group, TPG=32 tiles
    const int rowBlocks = N / 64;            // 64 rows/block (16/wave)
    kde_f16v14<<<rowBlocks * colGroups, 256, 0, stream>>>(xf, df, xn_u, dn_s, out,
                                                          colGroups);
}

// Round 2
// 80.986 us; speedup vs baseline: 1.0689x; 1.0689x over previous
//
#include <hip/hip_runtime.h>
#include <math.h>

// KDE via GEMM trick, v15 = v13 shape + algebraic VALU cut + launch fusion.
//   density[i] = (1/M) * sum_j exp2(2c*dot(x_i,d_j) - c|x_i|^2 - c|d_j|^2 - log2 M)
// v15 folds 2c into the A operand (xf = 2c*x in fp16) and feeds the row
// term u_i = -c|x|^2 - log2M in as the MFMA C-operand init (zero-cost).
// Per element: exp2 + 1 fmaf (was exp2 + 2 fmaf). d_out zeroing fused
// into prep (drops the memset dispatch).
//
// CROSS-ROUND MODEL (r9-v14): main pinned at ~29-30us across THREE
// structures: direct-stream (r12), LDS-shared 4w (v13, 85.81), LDS-shared
// 8w (v14, 86.56). v13<->v14 A/B: 2x per-CU LDS traffic + 2x B-VMEM + 2x
// waves/SIMD => +0.75us. LDS volume, VMEM volume, and occupancy all
// falsified as binding. Remaining reducible terms: per-element fmaf
// (~1.5-2us, cut here), one launch (~1-2us, cut here). If v15 lands >=85,
// the floor is external (harness fill 42.5us @79% HBM + restore/gaps +
// MFMA ~8us/CU + trans ~7-11us/CU irreducible) -> ROOFLINE.
//
// Fragment mappings (verified end-to-end rounds 2-14):
//   A: lane holds A[m=lane&15][k=(lane>>4)*8+j]
//   B: lane holds B^T row-major: col=lane&15, k=(lane>>4)*8+j
//   C/D: col=lane&15, row=(lane>>4)*4+reg
// global_load_lds: LDS dest = wave-uniform base + lane*16 (verified m104);
// df's fragment-major layout matches exactly.
// fp16 single-pass accuracy verified r4-v14: absmax ~2.8e-17 vs 2.4e-16.

#define D_DIM 128
#define TPG   32   // 16-col tiles per col-group (512 cols); 16 pairs

typedef _Float16 f16x8 __attribute__((ext_vector_type(8)));
typedef _Float16 f16x4 __attribute__((ext_vector_type(4)));
typedef __attribute__((ext_vector_type(4))) float f32x4;

#define C2F   ((float)(0.5 / 2.50662827463100050242 * 1.44269504088896340736))
#define TWOC2 (2.0f * C2F)

// ---- prep: fp32 -> fp16 fragment-major + pre-scaled norms + out zero ----
// x-side fragments pre-scaled by 2c so main's MFMA emits 2c*dot directly.
__global__ __launch_bounds__(256)
void prep_kernel(const float* __restrict__ x, const float* __restrict__ data,
                 _Float16* __restrict__ xf, _Float16* __restrict__ df,
                 float* __restrict__ xn_u, float* __restrict__ dn_s,
                 float* __restrict__ out, int xThreads, float negLogM) {
    const int gid = blockIdx.x * 256 + threadIdx.x;
    const int which = (gid >= xThreads);
    const int id = which ? (gid - xThreads) : gid;
    const int row = id >> 5, seg = id & 31;
    const float* src = which ? data : x;
    _Float16* dst = which ? df : xf;

    const float4 v = *(const float4*)&src[(size_t)row * D_DIM + seg * 4];

    const int t = row >> 4, r = row & 15;
    const int kc = seg >> 3, q = (seg >> 1) & 3, j0 = (seg & 1) * 4;
    const float sc = which ? 1.0f : TWOC2;   // scale x-side only
    f16x4 h;
    h[0] = (_Float16)(v.x * sc); h[1] = (_Float16)(v.y * sc);
    h[2] = (_Float16)(v.z * sc); h[3] = (_Float16)(v.w * sc);
    *(f16x4*)&dst[((size_t)(t * 4 + kc) * 64 + q * 16 + r) * 8 + j0] = h;

    // norms from UNSCALED values
    float nrm = fmaf(v.x, v.x, fmaf(v.y, v.y, fmaf(v.z, v.z, v.w * v.w)));
#pragma unroll
    for (int off = 1; off < 32; off <<= 1) nrm += __shfl_xor(nrm, off, 64);
    if (seg == 0) {
        if (which) dn_s[row] = -C2F * nrm;
        else {
            xn_u[row] = fmaf(-C2F, nrm, negLogM);
            out[row]  = 0.0f;                 // fused d_out zeroing
        }
    }
}

// ---- main: 4 waves x 32 rows, LDS-shared B, 2 tiles per barrier ----------
__global__ __launch_bounds__(256)
__attribute__((amdgpu_waves_per_eu(4, 4)))
void kde_f16v15(const _Float16* __restrict__ xf, const _Float16* __restrict__ df,
                const float* __restrict__ xn_u, const float* __restrict__ dn_s,
                float* __restrict__ out, int colGroups) {
    // Double buffer: each holds a PAIR of 16-col B tiles (2 x 4 KB).
    __shared__ _Float16 sh[2][4096];

    const int tid  = threadIdx.x;
    const int lane = tid & 63;
    const int w    = tid >> 6;
    const int q    = lane >> 4;
    const int r    = lane & 15;

    const int bid = blockIdx.x;
    const int cg  = bid % colGroups;
    const int rb  = bid / colGroups;
    const int rowBase  = rb * 128 + w * 32;  // this wave's 32 rows
    const int colTile0 = cg * TPG;

    // A fragments: 8 coalesced dwordx4 loads, once (2 row-tiles).
    f16x8 af0[4], af1[4];
    {
        const int tG0 = rb * 8 + w * 2;
#pragma unroll
        for (int kc = 0; kc < 4; ++kc) {
            af0[kc] = *(const f16x8*)&xf[((size_t)(tG0 * 4 + kc) * 64 + lane) * 8];
            af1[kc] = *(const f16x8*)&xf[((size_t)((tG0 + 1) * 4 + kc) * 64 + lane) * 8];
        }
    }

    // Row terms, consumed as MFMA C-operand init (zero per-tile cost).
    const f32x4 u0 = *(const f32x4*)&xn_u[rowBase + q * 4];
    const f32x4 u1 = *(const f32x4*)&xn_u[rowBase + 16 + q * 4];

    f32x4 srow0 = (f32x4){0.f, 0.f, 0.f, 0.f};
    f32x4 srow1 = (f32x4){0.f, 0.f, 0.f, 0.f};

    const _Float16* dbase = &df[(size_t)colTile0 * 2048];   // 2048 halves/tile
    const float*    nbase = &dn_s[colTile0 * 16 + r];

    // Stage pair p into buffer buf: 8 chunks of 1 KB, 2 per wave.
    auto stagePair = [&](int p, int buf) {
#pragma unroll
        for (int i = 0; i < 2; ++i) {
            const int c  = w * 2 + i;          // 0..7
            const int m  = c >> 2, kc = c & 3;
            const _Float16* g = &dbase[(size_t)(p * 2 + m) * 2048 + (size_t)kc * 512 + (size_t)lane * 8];
            __builtin_amdgcn_global_load_lds(
                (const __attribute__((address_space(1))) void*)g,
                (__attribute__((address_space(3))) void*)&sh[buf][c * 512], 16, 0, 0);
        }
    };

// Compute one 16-col tile (member M of the current pair) from LDS.
// Accumulators start at u0/u1 via the MFMA C input: final a[e] is the full
// exp2 argument minus the column term (applied via edv multiply).
#define TILE(BUF, M, DVV)                                                         \
    {                                                                             \
        f16x8 b0 = *(const f16x8*)&sh[BUF][((M) * 4 + 0) * 512 + lane * 8];       \
        f16x8 b1 = *(const f16x8*)&sh[BUF][((M) * 4 + 1) * 512 + lane * 8];       \
        f16x8 b2 = *(const f16x8*)&sh[BUF][((M) * 4 + 2) * 512 + lane * 8];       \
        f16x8 b3 = *(const f16x8*)&sh[BUF][((M) * 4 + 3) * 512 + lane * 8];       \
        f32x4 a0 = __builtin_amdgcn_mfma_f32_16x16x32_f16(af0[0], b0, u0, 0, 0, 0); \
        f32x4 a1 = __builtin_amdgcn_mfma_f32_16x16x32_f16(af1[0], b0, u1, 0, 0, 0); \
        a0 = __builtin_amdgcn_mfma_f32_16x16x32_f16(af0[1], b1, a0, 0, 0, 0);     \
        a1 = __builtin_amdgcn_mfma_f32_16x16x32_f16(af1[1], b1, a1, 0, 0, 0);     \
        a0 = __builtin_amdgcn_mfma_f32_16x16x32_f16(af0[2], b2, a0, 0, 0, 0);     \
        a1 = __builtin_amdgcn_mfma_f32_16x16x32_f16(af1[2], b2, a1, 0, 0, 0);     \
        a0 = __builtin_amdgcn_mfma_f32_16x16x32_f16(af0[3], b3, a0, 0, 0, 0);     \
        a1 = __builtin_amdgcn_mfma_f32_16x16x32_f16(af1[3], b3, a1, 0, 0, 0);     \
        const float edv_ = __builtin_amdgcn_exp2f(DVV);                           \
        srow0[0] = fmaf(__builtin_amdgcn_exp2f(a0[0]), edv_, srow0[0]);           \
        srow0[1] = fmaf(__builtin_amdgcn_exp2f(a0[1]), edv_, srow0[1]);           \
        srow0[2] = fmaf(__builtin_amdgcn_exp2f(a0[2]), edv_, srow0[2]);           \
        srow0[3] = fmaf(__builtin_amdgcn_exp2f(a0[3]), edv_, srow0[3]);           \
        srow1[0] = fmaf(__builtin_amdgcn_exp2f(a1[0]), edv_, srow1[0]);           \
        srow1[1] = fmaf(__builtin_amdgcn_exp2f(a1[1]), edv_, srow1[1]);           \
        srow1[2] = fmaf(__builtin_amdgcn_exp2f(a1[2]), edv_, srow1[2]);           \
        srow1[3] = fmaf(__builtin_amdgcn_exp2f(a1[3]), edv_, srow1[3]);           \
    }

    stagePair(0, 0);
    // dv prologue loads (consumed in iteration 0; thereafter one pair ahead).
    float dv0 = nbase[0];
    float dv1 = nbase[16];

#pragma unroll 1
    for (int p = 0; p < TPG / 2; ++p) {
        const int buf = p & 1;
        __syncthreads();                    // drains stage(p) (issued a full
                                            // compute phase ago) + frees buf^1
        float ndv0 = dv0, ndv1 = dv1;
        if (p + 1 < TPG / 2) {
            stagePair(p + 1, buf ^ 1);      // in flight across this compute
            ndv0 = nbase[(p * 2 + 2) * 16]; // dv prefetch: one pair ahead
            ndv1 = nbase[(p * 2 + 3) * 16];
        }
        TILE(buf, 0, dv0);
        TILE(buf, 1, dv1);
        dv0 = ndv0; dv1 = ndv1;
    }

#undef TILE

    // Reduce over the 16 col-lanes (r) and accumulate to out.
#pragma unroll
    for (int p = 0; p < 4; ++p) {
        float s = srow0[p];
        s += __shfl_xor(s, 1, 64);
        s += __shfl_xor(s, 2, 64);
        s += __shfl_xor(s, 4, 64);
        s += __shfl_xor(s, 8, 64);
        if (r == 0) atomicAdd(&out[rowBase + q * 4 + p], s);
        float s1 = srow1[p];
        s1 += __shfl_xor(s1, 1, 64);
        s1 += __shfl_xor(s1, 2, 64);
        s1 += __shfl_xor(s1, 4, 64);
        s1 += __shfl_xor(s1, 8, 64);
        if (r == 0) atomicAdd(&out[rowBase + 16 + q * 4 + p], s1);
    }
}

// ---------------- fallback: round-1 VALU kernel (any size, no ws) ---------
#define BN 128
#define BM 128
#define KT 32
#define LDSS 132

__global__ __launch_bounds__(256, 4)
void kde_valu(const float* __restrict__ x, const float* __restrict__ data,
              float* __restrict__ out, int N, int M) {
    __shared__ float xs[KT][LDSS];
    __shared__ float dsh[KT][LDSS];
    __shared__ float xn_s[BN];
    __shared__ float dn_s[BM];
    const int tid = threadIdx.x;
    const int ty = tid >> 4, tx = tid & 15;
    const int rowBase = blockIdx.y * BN, colBase = blockIdx.x * BM;
    float acc[8][8];
#pragma unroll
    for (int i = 0; i < 8; ++i)
#pragma unroll
        for (int j = 0; j < 8; ++j) acc[i][j] = 0.0f;
    float normAcc = 0.0f;
    for (int kc = 0; kc < D_DIM; kc += KT) {
        __syncthreads();
#pragma unroll
        for (int i = 0; i < 4; ++i) {
            const int idx = tid + i * 256;
            const int row = idx >> 3, kq = idx & 7;
            const float4 v = *(const float4*)&x[(size_t)(rowBase + row) * D_DIM + kc + kq * 4];
            xs[kq * 4 + 0][row] = v.x; xs[kq * 4 + 1][row] = v.y;
            xs[kq * 4 + 2][row] = v.z; xs[kq * 4 + 3][row] = v.w;
            const float4 wv = *(const float4*)&data[(size_t)(colBase + row) * D_DIM + kc + kq * 4];
            dsh[kq * 4 + 0][row] = wv.x; dsh[kq * 4 + 1][row] = wv.y;
            dsh[kq * 4 + 2][row] = wv.z; dsh[kq * 4 + 3][row] = wv.w;
        }
        __syncthreads();
        {
            const float* col = (tid < 128) ? &xs[0][tid] : &dsh[0][tid - 128];
#pragma unroll
            for (int k = 0; k < KT; ++k) { const float v = col[k * LDSS]; normAcc = fmaf(v, v, normAcc); }
        }
#pragma unroll
        for (int k = 0; k < KT; ++k) {
            float a[8], b[8];
            *(float4*)&a[0] = *(const float4*)&xs[k][ty * 8];
            *(float4*)&a[4] = *(const float4*)&xs[k][ty * 8 + 4];
            *(float4*)&b[0] = *(const float4*)&dsh[k][tx * 4];
            *(float4*)&b[4] = *(const float4*)&dsh[k][64 + tx * 4];
#pragma unroll
            for (int i = 0; i < 8; ++i)
#pragma unroll
                for (int j = 0; j < 8; ++j) acc[i][j] = fmaf(a[i], b[j], acc[i][j]);
        }
    }
    if (tid < 128) xn_s[tid] = normAcc; else dn_s[tid - 128] = normAcc;
    __syncthreads();
    const float C2 = C2F;
    const float negLogM = -log2f((float)M);
#pragma unroll
    for (int i = 0; i < 8; ++i) {
        const int row = ty * 8 + i;
        const float xnr = xn_s[row];
        float s = 0.0f;
#pragma unroll
        for (int j = 0; j < 8; ++j) {
            const int col = (j < 4) ? (tx * 4 + j) : (64 + tx * 4 + (j - 4));
            const float sq = xnr + dn_s[col] - 2.0f * acc[i][j];
            s += exp2f(fmaf(-C2, sq, negLogM));
        }
#pragma unroll
        for (int off = 1; off < 16; off <<= 1) s += __shfl_xor(s, off, 64);
        if (tx == 0) atomicAdd(&out[rowBase + row], s);
    }
}

extern "C" void kernel_launch(void* const* d_in, const int* in_sizes, int n_in,
                              void* d_out, int out_size, void* d_ws, size_t ws_size,
                              hipStream_t stream) {
    const float* x    = (const float*)d_in[0];
    const float* data = (const float*)d_in[1];
    float* out = (float*)d_out;
    const int N = in_sizes[0] / D_DIM;
    const int M = in_sizes[1] / D_DIM;

    const size_t need = (size_t)(N + M) * D_DIM * 2 + (size_t)(N + M) * 4;
    if (ws_size < need || (N & 127) || (M & 511)) {
        hipMemsetAsync(d_out, 0, (size_t)out_size * sizeof(float), stream);
        dim3 grid(M / BM, N / BN);
        kde_valu<<<grid, 256, 0, stream>>>(x, data, out, N, M);
        return;
    }

    _Float16* xf = (_Float16*)d_ws;
    _Float16* df = xf + (size_t)N * D_DIM;
    float* xn_u = (float*)(df + (size_t)M * D_DIM);
    float* dn_s = xn_u + N;

    const float negLogM = -log2f((float)M);
    const int xThreads = N * 32;
    const int totThreads = (N + M) * 32;
    prep_kernel<<<totThreads / 256, 256, 0, stream>>>(x, data, xf, df, xn_u, dn_s,
                                                      out, xThreads, negLogM);

    const int colGroups = M / 512;           // 512 cols/group, TPG=32 tiles
    const int rowBlocks = N / 128;
    kde_f16v15<<<rowBlocks * colGroups, 256, 0, stream>>>(xf, df, xn_u, dn_s, out,
                                                          colGroups);
}